// Round 6
// baseline (496.400 us; speedup 1.0000x reference)
//
#include <hip/hip_runtime.h>

typedef unsigned short u16;
typedef __attribute__((ext_vector_type(8))) short short8;
typedef __attribute__((ext_vector_type(4))) float floatx4;

#define NN_TOT 135168   // 4096 * 33

#define WAITVM(N) asm volatile("s_waitcnt vmcnt(" #N ")" ::: "memory")
#define WAITLGKM0 asm volatile("s_waitcnt lgkmcnt(0)" ::: "memory")
#define VMFENCE   asm volatile("" ::: "memory")   // compiler fence: pins vmem issue order

// ---- compile-time skeleton (from SKELETON_EDGES, incl. self-loops) ----
static constexpr int NBCNT[33] = {2,2,2,2,2,2,2,1,1,1,1,3,3,2,2,4,4,2,2,2,2,1,1,3,3,2,2,3,3,2,2,2,2};
static constexpr int NBR[33][4] = {
 {1,4,0,0},{0,2,0,0},{1,3,0,0},{2,7,0,0},{0,5,0,0},{4,6,0,0},{5,8,0,0},
 {3,0,0,0},{6,0,0,0},{10,0,0,0},{9,0,0,0},
 {12,13,23,0},{11,14,24,0},{11,15,0,0},{12,16,0,0},
 {13,17,19,21},{14,18,20,22},
 {15,19,0,0},{16,20,0,0},{15,17,0,0},{16,18,0,0},{15,0,0,0},{16,0,0,0},
 {11,24,25,0},{12,23,26,0},{23,27,0,0},{24,28,0,0},
 {25,29,31,0},{26,30,32,0},{27,31,0,0},{28,32,0,0},{29,27,0,0},{30,28,0,0}};
static constexpr float R2 = 0.70710678f, R3 = 0.57735027f, R4 = 0.5f, R5 = 0.44721360f;
static constexpr float DINV[33] = {R3,R3,R3,R3,R3,R3,R3, R2,R2,R2,R2, R4,R4, R3,R3, R5,R5,
                                   R3,R3,R3,R3, R2,R2, R4,R4, R3,R3, R4,R4, R3,R3,R3,R3};

__device__ __forceinline__ float bf2f(u16 u) {
  unsigned int v = ((unsigned int)u) << 16; float f; __builtin_memcpy(&f, &v, 4); return f;
}
__device__ __forceinline__ u16 f2bf(float f) {
  unsigned int u; __builtin_memcpy(&u, &f, 4);
  return (u16)((u + 0x7fffu + ((u >> 16) & 1u)) >> 16);
}
__device__ __forceinline__ float ldin(const void* p, int i, int isbf) {
  return isbf ? bf2f(((const u16*)p)[i]) : ((const float*)p)[i];
}
__device__ __forceinline__ void gload_lds16(const u16* g, u16* l) {
  __builtin_amdgcn_global_load_lds((const __attribute__((address_space(1))) unsigned int*)g,
                                   (__attribute__((address_space(3))) unsigned int*)l, 16, 0, 0);
}
// swizzled LDS offset (u16 units): row stride 32 u16; 16B chunk XOR'd by row bits
__device__ __forceinline__ int lof(int row, int qq) {
  return row*32 + ((qq ^ ((row >> 1) & 3)) * 8);
}

// ---- dtype detector (unchanged) ----
__global__ __launch_bounds__(256) void detect_kernel(const u16* __restrict__ x,
                                                     int* __restrict__ flag)
{
  __shared__ int cnt[256];
  const int t = threadIdx.x;
  int c = 0;
  for (int j = 0; j < 16; ++j) {
    u16 u = x[(t*16 + j)*2];
    int e = (u >> 7) & 0xFF;
    c += (e >= 118 && e <= 130) ? 1 : 0;
  }
  cnt[t] = c;
  __syncthreads();
  if (t == 0) {
    int s = 0;
    for (int i = 0; i < 256; ++i) s += cnt[i];
    *flag = (s > 2048) ? 1 : 0;   // 1 = bf16 inputs, 0 = fp32 inputs
  }
}

// ---- W transpose + canonicalize to bf16: Wt[n][k] = W[k][n] ----
__global__ __launch_bounds__(256) void transpose_kernel(const void* __restrict__ w0,
    const void* __restrict__ w1, const void* __restrict__ w2, u16* __restrict__ Wt,
    const int* __restrict__ flag)
{
  const int m = blockIdx.x >> 4;
  const int nb = (blockIdx.x & 15) * 16;
  const void* W = m == 0 ? w0 : (m == 1 ? w1 : w2);
  u16* O = Wt + (size_t)m * 65536;
  const int t = threadIdx.x;
  const int lane = t & 63, wv = t >> 6;
  const int isbf = *flag;
  if (isbf) {
    const u16* Wb = (const u16*)W;
#pragma unroll
    for (int nn = 0; nn < 4; ++nn) {
      const int n = nb + nn*4 + wv;
#pragma unroll
      for (int j = 0; j < 4; ++j) {
        const int k = lane + 64*j;
        O[n*256 + k] = Wb[k*256 + n];
      }
    }
  } else {
    const float* Wf = (const float*)W;
#pragma unroll
    for (int nn = 0; nn < 4; ++nn) {
      const int n = nb + nn*4 + wv;
#pragma unroll
      for (int j = 0; j < 4; ++j) {
        const int k = lane + 64*j;
        O[n*256 + k] = f2bf(Wf[k*256 + n]);
      }
    }
  }
}

// ---- init: wq = wh@wc, bq = bh@wc + bc, zero stat replicas ----
__global__ __launch_bounds__(256) void init_kernel(const void* __restrict__ wh,
    const void* __restrict__ bh, const void* __restrict__ wc, const void* __restrict__ bc,
    float* __restrict__ wq, float* __restrict__ bq, float* __restrict__ repl,
    const int* __restrict__ flag)
{
  const int idx = blockIdx.x*256 + threadIdx.x;
  for (int i = idx; i < 3*64*512; i += 65*256) repl[i] = 0.f;
  const int isbf = *flag;
  const int t = threadIdx.x;
  const int lane = t & 63;
  if (blockIdx.x < 64) {
    const int r = blockIdx.x*4 + (t >> 6);    // wq row, one per wave
    float a0=0.f, a1=0.f, a2=0.f, a3=0.f;
#pragma unroll
    for (int j = 0; j < 4; ++j) {
      const int k = lane + 64*j;
      const float w = ldin(wh, r*256 + k, isbf);
      a0 += w*ldin(wc, k*4+0, isbf); a1 += w*ldin(wc, k*4+1, isbf);
      a2 += w*ldin(wc, k*4+2, isbf); a3 += w*ldin(wc, k*4+3, isbf);
    }
#pragma unroll
    for (int off = 32; off; off >>= 1) {
      a0 += __shfl_xor(a0, off); a1 += __shfl_xor(a1, off);
      a2 += __shfl_xor(a2, off); a3 += __shfl_xor(a3, off);
    }
    if (lane == 0) { wq[r*4+0]=a0; wq[r*4+1]=a1; wq[r*4+2]=a2; wq[r*4+3]=a3; }
  } else if (t < 64) {
    float s0=0.f, s1=0.f, s2=0.f, s3=0.f;
#pragma unroll
    for (int j = 0; j < 4; ++j) {
      const int k = lane + 64*j;
      const float b = ldin(bh, k, isbf);
      s0 += b*ldin(wc, k*4+0, isbf); s1 += b*ldin(wc, k*4+1, isbf);
      s2 += b*ldin(wc, k*4+2, isbf); s3 += b*ldin(wc, k*4+3, isbf);
    }
#pragma unroll
    for (int off = 32; off; off >>= 1) {
      s0 += __shfl_xor(s0, off); s1 += __shfl_xor(s1, off);
      s2 += __shfl_xor(s2, off); s3 += __shfl_xor(s3, off);
    }
    if (lane == 0) {
      bq[0] = s0 + ldin(bc, 0, isbf); bq[1] = s1 + ldin(bc, 1, isbf);
      bq[2] = s2 + ldin(bc, 2, isbf); bq[3] = s3 + ldin(bc, 3, isbf);
    }
  }
}

// ---- FUSED layer: H = Ahat @ (act(Ag) @ W) + b, plus BN stats ----
// Geometry: block = 2 graphs (66 rows), wave (gi,h), grid 2048.
// Pipeline: B DMA 1 step ahead (2 bufs), A 2 steps ahead (ACT0: DMA, 3 bufs;
// ACT1: regs, 2 slots + BN-ReLU ds_write 1 ahead). Per-step issue order
// [B-group | fence | A-group] is pinned by compiler fences so counted vmcnt
// is robust: steady consume-wait leaves A(kc+1)+B(kc+1)+A(kc+2) = 6 (8 for
// the special wave with 2 A ops) in flight -> A gets a 2-step latency window.
// scale/shift staged once into LDS (sS); per-step VMEM stream shrinks by 4.
template<int ACT>
__global__ __launch_bounds__(256, 3) void fused_kernel(
    const void* __restrict__ Ag, const u16* __restrict__ Bt,
    const float* __restrict__ fscale, const float* __restrict__ fshift,
    const void* __restrict__ bias, u16* __restrict__ H,
    float* __restrict__ repl, const int* __restrict__ flag)
{
  // u16 units: sA[3] @ 0/2592/5184 (81 rows x 32), sB[2] @ 7776/15968,
  // sS f32[512] @ 24160 (byte 48320). Total 25184 u16 = 50368 B -> 3 blocks/CU.
  // Epilogue overlays Tl = u16[66][264] @ 0 (17424 u16).
  __shared__ __align__(16) u16 smem[25184];
  const int tid = threadIdx.x;
  const int lane = tid & 63, w = tid >> 6;
  const int gi = w >> 1, h = w & 1;
  const int fr = lane & 15, q = lane >> 4;
  const int lr = lane >> 2, cq = lane & 3;
  const int swz = (lr >> 1) & 3;
  const int r0 = tid >> 2;
  const int c8 = (tid & 3) * 8;
  const size_t R0 = (size_t)blockIdx.x * 66;
  const int dtf = *flag;
  const int isbf = (ACT == 0) ? dtf : 1;
  const u16* Ab = (const u16*)Ag;
  const float* Af = (const float*)Ag;
  float* const sS = (float*)(smem + 24160);

  floatx4 acc[3][8];
#pragma unroll
  for (int t = 0; t < 3; ++t)
#pragma unroll
    for (int j = 0; j < 8; ++j) acc[t][j] = (floatx4){0.f, 0.f, 0.f, 0.f};

  auto sAbuf = [&](int i) -> u16* { return smem + i*2592; };
  auto sBbuf = [&](int i) -> u16* { return smem + 7776 + i*8192; };

  auto issueB = [&](int t) {               // tile t -> B buf t&1 (4 DMA / wave)
    u16* dst = sBbuf(t & 1);
    const int k0 = t * 32;
#pragma unroll
    for (int i = 0; i < 4; ++i)
      gload_lds16(Bt + (w*64 + i*16 + lr)*256 + k0 + (cq ^ swz)*8,
                  dst + (w*64 + i*16)*32);
  };
  auto issueA_dma = [&](int t) {           // ACT0: tile t -> A buf t%3 (1-2 DMA)
    u16* dst = sAbuf(t % 3);
    const int k0 = t * 32;
    gload_lds16(Ab + (R0 + w*16 + lr)*256 + k0 + (cq ^ swz)*8, dst + (w*16)*32);
    if (w == 0) {
      size_t rg = R0 + 64 + lr;
      if (rg >= NN_TOT) rg = NN_TOT - 1;   // clamp (garbage rows masked later)
      gload_lds16(Ab + rg*256 + k0 + (cq ^ swz)*8, dst + 64*32);
    }
  };

  uint4 regA[2], regA2[2];
  auto issueA_reg = [&](int t) {           // ACT1: tile t -> reg slot t&1 (1-2 loads)
    const int k0 = t * 32;
    regA[t & 1] = *(const uint4*)(Ab + (R0 + r0)*256 + k0 + c8);
    if (tid >= 248)
      regA2[t & 1] = *(const uint4*)(Ab + (R0 + 64 + ((tid - 248) >> 2))*256 + k0 + c8);
  };
  auto writeA = [&](int t) {               // BN-ReLU from sS, swizzled ds_write -> buf t&1
    u16* dst = sAbuf(t & 1);
    const int k0 = t * 32;
    const float4 s0 = *(const float4*)(sS + k0 + c8);
    const float4 s1 = *(const float4*)(sS + k0 + c8 + 4);
    const float4 t0 = *(const float4*)(sS + 256 + k0 + c8);
    const float4 t1 = *(const float4*)(sS + 256 + k0 + c8 + 4);
    const float sc[8] = {s0.x,s0.y,s0.z,s0.w, s1.x,s1.y,s1.z,s1.w};
    const float sh[8] = {t0.x,t0.y,t0.z,t0.w, t1.x,t1.y,t1.z,t1.w};
    {
      const u16* us = (const u16*)&regA[t & 1];
      u16 ov[8];
#pragma unroll
      for (int j = 0; j < 8; ++j)
        ov[j] = f2bf(fmaxf(0.f, fmaf(bf2f(us[j]), sc[j], sh[j])));
      *(uint4*)(dst + r0*32 + ((cq ^ ((r0 >> 1) & 3))*8)) = *(const uint4*)ov;
    }
    if (tid >= 248) {
      const int rr = 64 + ((tid - 248) >> 2);
      const u16* us = (const u16*)&regA2[t & 1];
      u16 ov[8];
#pragma unroll
      for (int j = 0; j < 8; ++j)
        ov[j] = f2bf(fmaxf(0.f, fmaf(bf2f(us[j]), sc[j], sh[j])));
      *(uint4*)(dst + rr*32 + ((cq ^ ((rr >> 1) & 3))*8)) = *(const uint4*)ov;
    }
  };

  auto computeP = [&](const u16* cA, const u16* cB) {
    short8 a[3], b[8];
#pragma unroll
    for (int t = 0; t < 3; ++t)
      a[t] = *(const short8*)(cA + lof(gi*33 + t*16 + fr, q));
#pragma unroll
    for (int nf = 0; nf < 8; ++nf)
      b[nf] = *(const short8*)(cB + lof(h*128 + nf*16 + fr, q));
#pragma unroll
    for (int t = 0; t < 3; ++t)
#pragma unroll
      for (int nf = 0; nf < 8; ++nf)
        acc[t][nf] = __builtin_amdgcn_mfma_f32_16x16x32_bf16(a[t], b[nf], acc[t][nf], 0, 0, 0);
  };

  // ---------------- K loop ----------------
  if (ACT == 0 && !isbf) {
    // fp32 fallback (cold path; runtime inputs are bf16): simple drain loop.
    for (int kc = 0; kc < 8; ++kc) {
      const int k0 = kc * 32;
      __syncthreads();
      {
        const float* ap = Af + (R0 + r0)*256 + k0 + c8;
        float4 p0 = *(const float4*)(ap);
        float4 p1 = *(const float4*)(ap + 4);
        u16 ov[8];
        ov[0]=f2bf(p0.x); ov[1]=f2bf(p0.y); ov[2]=f2bf(p0.z); ov[3]=f2bf(p0.w);
        ov[4]=f2bf(p1.x); ov[5]=f2bf(p1.y); ov[6]=f2bf(p1.z); ov[7]=f2bf(p1.w);
        *(uint4*)(sAbuf(0) + r0*32 + ((cq ^ ((r0 >> 1) & 3))*8)) = *(const uint4*)ov;
      }
      if (tid < 8) {
        const int rr = 64 + (tid >> 2);
        const float* ap = Af + (R0 + rr)*256 + k0 + c8;
        float4 p0 = *(const float4*)(ap);
        float4 p1 = *(const float4*)(ap + 4);
        u16 ov[8];
        ov[0]=f2bf(p0.x); ov[1]=f2bf(p0.y); ov[2]=f2bf(p0.z); ov[3]=f2bf(p0.w);
        ov[4]=f2bf(p1.x); ov[5]=f2bf(p1.y); ov[6]=f2bf(p1.z); ov[7]=f2bf(p1.w);
        *(uint4*)(sAbuf(0) + rr*32 + ((cq ^ ((rr >> 1) & 3))*8)) = *(const uint4*)ov;
      }
#pragma unroll
      for (int i = 0; i < 4; ++i)
        gload_lds16(Bt + (w*64 + i*16 + lr)*256 + k0 + (cq ^ swz)*8,
                    sBbuf(0) + (w*64 + i*16)*32);
      __syncthreads();            // full drain (correctness)
      computeP(sAbuf(0), sBbuf(0));
    }
  } else {
    if (ACT == 1) {
      const float f0 = fscale[tid], f1 = fshift[tid];
      WAITVM(0);
      sS[tid] = f0; sS[256 + tid] = f1;
      WAITLGKM0;
    }
    // prologue: B(0); A(0), A(1)
    issueB(0);
    VMFENCE;
    if (ACT == 0) { issueA_dma(0); issueA_dma(1); }
    else          { issueA_reg(0); issueA_reg(1); }
    if (ACT == 1) {
      __builtin_amdgcn_s_barrier();   // sS visible to all waves (raw: DMAs stay in flight)
      writeA(0);                       // compiler auto-waits regA[0]
      WAITLGKM0;
    }
    const bool sp = (ACT == 0) ? (w == 0) : (w == 3);   // special wave: 2 A ops/step
#pragma unroll
    for (int kc = 0; kc < 8; ++kc) {
      if (kc < 7) issueB(kc + 1);
      VMFENCE;
      if (kc < 6) { if (ACT == 0) issueA_dma(kc + 2); else issueA_reg(kc + 2); }
      // consume-wait for tile kc: keep [A(kc+1), B(kc+1), A(kc+2)] in flight
      if (kc < 6)       { if (sp) { WAITVM(8); } else { WAITVM(6); } }
      else if (kc == 6) { if (sp) { WAITVM(6); } else { WAITVM(5); } }
      else              { WAITVM(0); }
      __builtin_amdgcn_sched_barrier(0);
      __builtin_amdgcn_s_barrier();
      computeP(ACT == 0 ? sAbuf(kc % 3) : sAbuf(kc & 1), sBbuf(kc & 1));
      if (ACT == 1 && kc < 7) {
        writeA(kc + 1);      // auto-wait on regA slot; B/A prefetches stay in flight
        WAITLGKM0;
      }
    }
  }

  // ---- epilogue 1: T -> LDS (bf16, rows<33 only; garbage rows discarded) ----
  __syncthreads();
  u16* const Tl = smem;     // [66][264]
#pragma unroll
  for (int t = 0; t < 3; ++t)
#pragma unroll
    for (int nf = 0; nf < 8; ++nf)
#pragma unroll
      for (int r = 0; r < 4; ++r) {
        const int row = t*16 + q*4 + r;
        if (row < 33)
          Tl[(gi*33 + row)*264 + h*128 + nf*16 + fr] = f2bf(acc[t][nf][r]);
      }
  __syncthreads();

  // ---- epilogue 2: graph-local skeleton aggregation + bias + stats ----
  const int g2 = tid >> 7, cp = tid & 127;
  const size_t Gg = (size_t)blockIdx.x*2 + g2;
  float a0[33], a1[33];
#pragma unroll
  for (int d = 0; d < 33; ++d) { a0[d] = 0.f; a1[d] = 0.f; }
#pragma unroll
  for (int s = 0; s < 33; ++s) {
    const unsigned int pk = *(const unsigned int*)(Tl + (g2*33 + s)*264 + cp*2);
    const float v0 = bf2f((u16)(pk & 0xffffu)) * DINV[s];
    const float v1 = bf2f((u16)(pk >> 16)) * DINV[s];
    a0[s] += v0; a1[s] += v1;                    // self loop
#pragma unroll
    for (int i = 0; i < NBCNT[s]; ++i) { a0[NBR[s][i]] += v0; a1[NBR[s][i]] += v1; }
  }
  const float bv0 = ldin(bias, cp*2,     dtf);
  const float bv1 = ldin(bias, cp*2 + 1, dtf);
  float s10 = 0.f, s20 = 0.f, s11 = 0.f, s21 = 0.f;
  u16* hg = H + Gg * (33*256);
#pragma unroll
  for (int d = 0; d < 33; ++d) {
    const float o0 = fmaf(a0[d], DINV[d], bv0);
    const float o1 = fmaf(a1[d], DINV[d], bv1);
    const unsigned int pw = (unsigned int)f2bf(o0) | ((unsigned int)f2bf(o1) << 16);
    *(unsigned int*)(hg + d*256 + cp*2) = pw;
    s10 += o0; s20 += o0*o0; s11 += o1; s21 += o1*o1;
  }
  float* r1p = repl + (Gg & 63)*512;
  atomicAdd(r1p + cp*2,           s10);
  atomicAdd(r1p + cp*2 + 1,       s11);
  atomicAdd(r1p + 256 + cp*2,     s20);
  atomicAdd(r1p + 256 + cp*2 + 1, s21);
}

// ---- finalize BN stats -> scale/shift ----
__global__ __launch_bounds__(256) void statfin_kernel(const float* __restrict__ repl,
    const void* __restrict__ gamma, const void* __restrict__ beta, float* __restrict__ fs,
    const int* __restrict__ flag)
{
  const int c = threadIdx.x;
  const int isbf = *flag;
  float s1 = 0.f, s2 = 0.f;
  for (int r = 0; r < 64; ++r) { s1 += repl[r*512 + c]; s2 += repl[r*512 + 256 + c]; }
  const float inv = 1.f / (float)NN_TOT;
  const float mu = s1 * inv;
  const float var = s2 * inv - mu*mu;
  const float rs = rsqrtf(var + 1e-5f);
  const float sc = rs * ldin(gamma, c, isbf);
  fs[c] = sc;
  fs[256 + c] = ldin(beta, c, isbf) - mu * sc;
}

// ---- fused layer3 + mean-pool + classifier: 1 wave per graph, 4 cols/lane ----
__global__ __launch_bounds__(256) void final_kernel(const u16* __restrict__ H,
    const float* __restrict__ fs, const float* __restrict__ wq,
    const float* __restrict__ bq, void* __restrict__ outp,
    const int* __restrict__ flag)
{
  const int tid = threadIdx.x;
  const int lane = tid & 63, wv = tid >> 6;
  const size_t g = (size_t)blockIdx.x * 4 + wv;
  const int isbf = *flag;
  const int c4 = lane * 4;
  const float4 scv = *(const float4*)(fs + c4);
  const float4 shv = *(const float4*)(fs + 256 + c4);
  const u16* hg = H + g * (33*256);
  float v0 = 0.f, v1 = 0.f, v2 = 0.f, v3 = 0.f;
#pragma unroll
  for (int s = 0; s < 33; ++s) {
    float a = DINV[s];
#pragma unroll
    for (int i = 0; i < NBCNT[s]; ++i) a += DINV[NBR[s][i]];
    const float ws = DINV[s] * a * (1.f/33.f);   // column-sum of Ahat / 33 (const-folded)
    const uint2 pk = *(const uint2*)(hg + s*256 + c4);
    v0 += ws * fmaxf(0.f, fmaf(bf2f((u16)(pk.x & 0xffffu)), scv.x, shv.x));
    v1 += ws * fmaxf(0.f, fmaf(bf2f((u16)(pk.x >> 16)),     scv.y, shv.y));
    v2 += ws * fmaxf(0.f, fmaf(bf2f((u16)(pk.y & 0xffffu)), scv.z, shv.z));
    v3 += ws * fmaxf(0.f, fmaf(bf2f((u16)(pk.y >> 16)),     scv.w, shv.w));
  }
  const float4 q0 = *(const float4*)(wq + (c4+0)*4);
  const float4 q1 = *(const float4*)(wq + (c4+1)*4);
  const float4 q2 = *(const float4*)(wq + (c4+2)*4);
  const float4 q3 = *(const float4*)(wq + (c4+3)*4);
  float p0 = v0*q0.x + v1*q1.x + v2*q2.x + v3*q3.x;
  float p1 = v0*q0.y + v1*q1.y + v2*q2.y + v3*q3.y;
  float p2 = v0*q0.z + v1*q1.z + v2*q2.z + v3*q3.z;
  float p3 = v0*q0.w + v1*q1.w + v2*q2.w + v3*q3.w;
#pragma unroll
  for (int off = 32; off; off >>= 1) {
    p0 += __shfl_xor(p0, off); p1 += __shfl_xor(p1, off);
    p2 += __shfl_xor(p2, off); p3 += __shfl_xor(p3, off);
  }
  if (lane == 0) {
    if (isbf) {
      u16* o = (u16*)outp + g*4;
      o[0]=f2bf(p0+bq[0]); o[1]=f2bf(p1+bq[1]); o[2]=f2bf(p2+bq[2]); o[3]=f2bf(p3+bq[3]);
    } else {
      float* o = (float*)outp + g*4;
      o[0]=p0+bq[0]; o[1]=p1+bq[1]; o[2]=p2+bq[2]; o[3]=p3+bq[3];
    }
  }
}

extern "C" void kernel_launch(void* const* d_in, const int* in_sizes, int n_in,
                              void* d_out, int out_size, void* d_ws, size_t ws_size,
                              hipStream_t stream)
{
  const void* x   = d_in[0];
  const void* w0  = d_in[1];
  const void* b0  = d_in[2];
  const void* g0  = d_in[3];
  const void* be0 = d_in[4];
  const void* w1  = d_in[5];
  const void* b1  = d_in[6];
  const void* g1  = d_in[7];
  const void* be1 = d_in[8];
  const void* w2  = d_in[9];
  const void* b2  = d_in[10];
  const void* g2  = d_in[11];
  const void* be2 = d_in[12];
  const void* wh  = d_in[13];
  const void* bh  = d_in[14];
  const void* wc  = d_in[15];
  const void* bc  = d_in[16];

  // Workspace: 66.8 MB total.
  char* ws = (char*)d_ws;
  float* wq   = (float*)(ws + 0);          // 1024 f
  float* bq   = (float*)(ws + 4096);       // 4 f
  float* fs   = (float*)(ws + 4608);       // 3 * 512 f
  int*   flag = (int*)  (ws + 12288);      // dtype flag
  float* repl = (float*)(ws + 16384);      // 3 * 64 * 512 f
  u16*   Wt   = (u16*)  (ws + 409600);     // 3 * 65536 bf16
  u16*   A    = (u16*)  (ws + 802816);     // 135168*256 bf16 (ends at 70,008,832)
  (void)in_sizes; (void)n_in; (void)out_size; (void)ws_size;

  detect_kernel<<<1, 256, 0, stream>>>((const u16*)x, flag);
  transpose_kernel<<<48, 256, 0, stream>>>(w0, w1, w2, Wt, flag);
  init_kernel<<<65, 256, 0, stream>>>(wh, bh, wc, bc, wq, bq, repl, flag);

  // layer 0 (gemm + aggregation + stats fused)
  fused_kernel<0><<<2048, 256, 0, stream>>>(x, Wt, nullptr, nullptr, b0, A, repl, flag);
  statfin_kernel<<<1, 256, 0, stream>>>(repl, g0, be0, fs, flag);
  // layer 1 (in-place)
  fused_kernel<1><<<2048, 256, 0, stream>>>(A, Wt + 65536, fs, fs + 256, b1, A, repl + 32768, flag);
  statfin_kernel<<<1, 256, 0, stream>>>(repl + 32768, g1, be1, fs + 512, flag);
  // layer 2 (in-place)
  fused_kernel<1><<<2048, 256, 0, stream>>>(A, Wt + 131072, fs + 512, fs + 768, b2, A, repl + 65536, flag);
  statfin_kernel<<<1, 256, 0, stream>>>(repl + 65536, g2, be2, fs + 1024, flag);
  // layer 3 + pool + classifier (folded)
  final_kernel<<<1024, 256, 0, stream>>>(A, fs + 1024, wq, bq, d_out, flag);
}

// Round 7
// 420.016 us; speedup vs baseline: 1.1819x; 1.1819x over previous
//
#include <hip/hip_runtime.h>

typedef unsigned short u16;
typedef __attribute__((ext_vector_type(8))) short short8;
typedef __attribute__((ext_vector_type(4))) float floatx4;

#define NN_TOT 135168   // 4096 * 33

#define WAITVM(N) asm volatile("s_waitcnt vmcnt(" #N ")" ::: "memory")
#define WAITLGKM0 asm volatile("s_waitcnt lgkmcnt(0)" ::: "memory")
#define VMFENCE   asm volatile("" ::: "memory")   // compiler fence: pins vmem issue order

// ---- compile-time skeleton (from SKELETON_EDGES, incl. self-loops) ----
static constexpr int NBCNT[33] = {2,2,2,2,2,2,2,1,1,1,1,3,3,2,2,4,4,2,2,2,2,1,1,3,3,2,2,3,3,2,2,2,2};
static constexpr int NBR[33][4] = {
 {1,4,0,0},{0,2,0,0},{1,3,0,0},{2,7,0,0},{0,5,0,0},{4,6,0,0},{5,8,0,0},
 {3,0,0,0},{6,0,0,0},{10,0,0,0},{9,0,0,0},
 {12,13,23,0},{11,14,24,0},{11,15,0,0},{12,16,0,0},
 {13,17,19,21},{14,18,20,22},
 {15,19,0,0},{16,20,0,0},{15,17,0,0},{16,18,0,0},{15,0,0,0},{16,0,0,0},
 {11,24,25,0},{12,23,26,0},{23,27,0,0},{24,28,0,0},
 {25,29,31,0},{26,30,32,0},{27,31,0,0},{28,32,0,0},{29,27,0,0},{30,28,0,0}};
static constexpr float R2 = 0.70710678f, R3 = 0.57735027f, R4 = 0.5f, R5 = 0.44721360f;
static constexpr float DINV[33] = {R3,R3,R3,R3,R3,R3,R3, R2,R2,R2,R2, R4,R4, R3,R3, R5,R5,
                                   R3,R3,R3,R3, R2,R2, R4,R4, R3,R3, R4,R4, R3,R3,R3,R3};

__device__ __forceinline__ float bf2f(u16 u) {
  unsigned int v = ((unsigned int)u) << 16; float f; __builtin_memcpy(&f, &v, 4); return f;
}
__device__ __forceinline__ u16 f2bf(float f) {
  unsigned int u; __builtin_memcpy(&u, &f, 4);
  return (u16)((u + 0x7fffu + ((u >> 16) & 1u)) >> 16);
}
__device__ __forceinline__ float ldin(const void* p, int i, int isbf) {
  return isbf ? bf2f(((const u16*)p)[i]) : ((const float*)p)[i];
}
__device__ __forceinline__ void gload_lds16(const u16* g, u16* l) {
  __builtin_amdgcn_global_load_lds((const __attribute__((address_space(1))) unsigned int*)g,
                                   (__attribute__((address_space(3))) unsigned int*)l, 16, 0, 0);
}
// swizzled LDS offset (u16 units): row stride 32 u16; 16B chunk XOR'd by row bits
__device__ __forceinline__ int lof(int row, int qq) {
  return row*32 + ((qq ^ ((row >> 1) & 3)) * 8);
}

// ---- dtype detector (unchanged) ----
__global__ __launch_bounds__(256) void detect_kernel(const u16* __restrict__ x,
                                                     int* __restrict__ flag)
{
  __shared__ int cnt[256];
  const int t = threadIdx.x;
  int c = 0;
  for (int j = 0; j < 16; ++j) {
    u16 u = x[(t*16 + j)*2];
    int e = (u >> 7) & 0xFF;
    c += (e >= 118 && e <= 130) ? 1 : 0;
  }
  cnt[t] = c;
  __syncthreads();
  if (t == 0) {
    int s = 0;
    for (int i = 0; i < 256; ++i) s += cnt[i];
    *flag = (s > 2048) ? 1 : 0;   // 1 = bf16 inputs, 0 = fp32 inputs
  }
}

// ---- W transpose + canonicalize to bf16: Wt[n][k] = W[k][n] ----
__global__ __launch_bounds__(256) void transpose_kernel(const void* __restrict__ w0,
    const void* __restrict__ w1, const void* __restrict__ w2, u16* __restrict__ Wt,
    const int* __restrict__ flag)
{
  const int m = blockIdx.x >> 4;
  const int nb = (blockIdx.x & 15) * 16;
  const void* W = m == 0 ? w0 : (m == 1 ? w1 : w2);
  u16* O = Wt + (size_t)m * 65536;
  const int t = threadIdx.x;
  const int lane = t & 63, wv = t >> 6;
  const int isbf = *flag;
  if (isbf) {
    const u16* Wb = (const u16*)W;
#pragma unroll
    for (int nn = 0; nn < 4; ++nn) {
      const int n = nb + nn*4 + wv;
#pragma unroll
      for (int j = 0; j < 4; ++j) {
        const int k = lane + 64*j;
        O[n*256 + k] = Wb[k*256 + n];
      }
    }
  } else {
    const float* Wf = (const float*)W;
#pragma unroll
    for (int nn = 0; nn < 4; ++nn) {
      const int n = nb + nn*4 + wv;
#pragma unroll
      for (int j = 0; j < 4; ++j) {
        const int k = lane + 64*j;
        O[n*256 + k] = f2bf(Wf[k*256 + n]);
      }
    }
  }
}

// ---- init: wq = wh@wc, bq = bh@wc + bc, zero stat replicas ----
__global__ __launch_bounds__(256) void init_kernel(const void* __restrict__ wh,
    const void* __restrict__ bh, const void* __restrict__ wc, const void* __restrict__ bc,
    float* __restrict__ wq, float* __restrict__ bq, float* __restrict__ repl,
    const int* __restrict__ flag)
{
  const int idx = blockIdx.x*256 + threadIdx.x;
  for (int i = idx; i < 3*64*512; i += 65*256) repl[i] = 0.f;
  const int isbf = *flag;
  const int t = threadIdx.x;
  const int lane = t & 63;
  if (blockIdx.x < 64) {
    const int r = blockIdx.x*4 + (t >> 6);    // wq row, one per wave
    float a0=0.f, a1=0.f, a2=0.f, a3=0.f;
#pragma unroll
    for (int j = 0; j < 4; ++j) {
      const int k = lane + 64*j;
      const float w = ldin(wh, r*256 + k, isbf);
      a0 += w*ldin(wc, k*4+0, isbf); a1 += w*ldin(wc, k*4+1, isbf);
      a2 += w*ldin(wc, k*4+2, isbf); a3 += w*ldin(wc, k*4+3, isbf);
    }
#pragma unroll
    for (int off = 32; off; off >>= 1) {
      a0 += __shfl_xor(a0, off); a1 += __shfl_xor(a1, off);
      a2 += __shfl_xor(a2, off); a3 += __shfl_xor(a3, off);
    }
    if (lane == 0) { wq[r*4+0]=a0; wq[r*4+1]=a1; wq[r*4+2]=a2; wq[r*4+3]=a3; }
  } else if (t < 64) {
    float s0=0.f, s1=0.f, s2=0.f, s3=0.f;
#pragma unroll
    for (int j = 0; j < 4; ++j) {
      const int k = lane + 64*j;
      const float b = ldin(bh, k, isbf);
      s0 += b*ldin(wc, k*4+0, isbf); s1 += b*ldin(wc, k*4+1, isbf);
      s2 += b*ldin(wc, k*4+2, isbf); s3 += b*ldin(wc, k*4+3, isbf);
    }
#pragma unroll
    for (int off = 32; off; off >>= 1) {
      s0 += __shfl_xor(s0, off); s1 += __shfl_xor(s1, off);
      s2 += __shfl_xor(s2, off); s3 += __shfl_xor(s3, off);
    }
    if (lane == 0) {
      bq[0] = s0 + ldin(bc, 0, isbf); bq[1] = s1 + ldin(bc, 1, isbf);
      bq[2] = s2 + ldin(bc, 2, isbf); bq[3] = s3 + ldin(bc, 3, isbf);
    }
  }
}

// ---- FUSED layer: H = Ahat @ (act(Ag) @ W) + b, plus BN stats ----
// Geometry: block = 2 graphs (66 rows), wave (gi,h), grid 2048.
// Pipeline: B DMA 1 step ahead (2 bufs), A 2 steps ahead (ACT0: DMA, 3 bufs;
// ACT1: regs, 2 slots + BN-ReLU ds_write 1 ahead). scale/shift hoisted to LDS.
// __launch_bounds__(256,2): reg footprint ~180 (84 VGPR + 96 AGPR acc) caps HW
// at 2 waves/SIMD; requesting 3 forces spill-to-scratch (r6: +70MB WRITE, +15us).
template<int ACT>
__global__ __launch_bounds__(256, 2) void fused_kernel(
    const void* __restrict__ Ag, const u16* __restrict__ Bt,
    const float* __restrict__ fscale, const float* __restrict__ fshift,
    const void* __restrict__ bias, u16* __restrict__ H,
    float* __restrict__ repl, const int* __restrict__ flag)
{
  // u16 units: sA[3] @ 0/2592/5184 (81 rows x 32), sB[2] @ 7776/15968,
  // sS f32[512] @ 24160 (byte 48320). Total 25184 u16 = 50368 B.
  // Epilogue overlays Tl = u16[66][264] @ 0 (17424 u16).
  __shared__ __align__(16) u16 smem[25184];
  const int tid = threadIdx.x;
  const int lane = tid & 63, w = tid >> 6;
  const int gi = w >> 1, h = w & 1;
  const int fr = lane & 15, q = lane >> 4;
  const int lr = lane >> 2, cq = lane & 3;
  const int swz = (lr >> 1) & 3;
  const int r0 = tid >> 2;
  const int c8 = (tid & 3) * 8;
  const size_t R0 = (size_t)blockIdx.x * 66;
  const int dtf = *flag;
  const int isbf = (ACT == 0) ? dtf : 1;
  const u16* Ab = (const u16*)Ag;
  const float* Af = (const float*)Ag;
  float* const sS = (float*)(smem + 24160);

  floatx4 acc[3][8];
#pragma unroll
  for (int t = 0; t < 3; ++t)
#pragma unroll
    for (int j = 0; j < 8; ++j) acc[t][j] = (floatx4){0.f, 0.f, 0.f, 0.f};

  auto sAbuf = [&](int i) -> u16* { return smem + i*2592; };
  auto sBbuf = [&](int i) -> u16* { return smem + 7776 + i*8192; };

  auto issueB = [&](int t) {               // tile t -> B buf t&1 (4 DMA / wave)
    u16* dst = sBbuf(t & 1);
    const int k0 = t * 32;
#pragma unroll
    for (int i = 0; i < 4; ++i)
      gload_lds16(Bt + (w*64 + i*16 + lr)*256 + k0 + (cq ^ swz)*8,
                  dst + (w*64 + i*16)*32);
  };
  auto issueA_dma = [&](int t) {           // ACT0: tile t -> A buf t%3 (1-2 DMA)
    u16* dst = sAbuf(t % 3);
    const int k0 = t * 32;
    gload_lds16(Ab + (R0 + w*16 + lr)*256 + k0 + (cq ^ swz)*8, dst + (w*16)*32);
    if (w == 0) {
      size_t rg = R0 + 64 + lr;
      if (rg >= NN_TOT) rg = NN_TOT - 1;   // clamp (garbage rows masked later)
      gload_lds16(Ab + rg*256 + k0 + (cq ^ swz)*8, dst + 64*32);
    }
  };

  uint4 regA[2], regA2[2];
  auto issueA_reg = [&](int t) {           // ACT1: tile t -> reg slot t&1 (1-2 loads)
    const int k0 = t * 32;
    regA[t & 1] = *(const uint4*)(Ab + (R0 + r0)*256 + k0 + c8);
    if (tid >= 248)
      regA2[t & 1] = *(const uint4*)(Ab + (R0 + 64 + ((tid - 248) >> 2))*256 + k0 + c8);
  };
  auto writeA = [&](int t) {               // BN-ReLU from sS, swizzled ds_write -> buf t&1
    u16* dst = sAbuf(t & 1);
    const int k0 = t * 32;
    const float4 s0 = *(const float4*)(sS + k0 + c8);
    const float4 s1 = *(const float4*)(sS + k0 + c8 + 4);
    const float4 t0 = *(const float4*)(sS + 256 + k0 + c8);
    const float4 t1 = *(const float4*)(sS + 256 + k0 + c8 + 4);
    const float sc[8] = {s0.x,s0.y,s0.z,s0.w, s1.x,s1.y,s1.z,s1.w};
    const float sh[8] = {t0.x,t0.y,t0.z,t0.w, t1.x,t1.y,t1.z,t1.w};
    {
      const u16* us = (const u16*)&regA[t & 1];
      u16 ov[8];
#pragma unroll
      for (int j = 0; j < 8; ++j)
        ov[j] = f2bf(fmaxf(0.f, fmaf(bf2f(us[j]), sc[j], sh[j])));
      *(uint4*)(dst + r0*32 + ((cq ^ ((r0 >> 1) & 3))*8)) = *(const uint4*)ov;
    }
    if (tid >= 248) {
      const int rr = 64 + ((tid - 248) >> 2);
      const u16* us = (const u16*)&regA2[t & 1];
      u16 ov[8];
#pragma unroll
      for (int j = 0; j < 8; ++j)
        ov[j] = f2bf(fmaxf(0.f, fmaf(bf2f(us[j]), sc[j], sh[j])));
      *(uint4*)(dst + rr*32 + ((cq ^ ((rr >> 1) & 3))*8)) = *(const uint4*)ov;
    }
  };

  auto computeP = [&](const u16* cA, const u16* cB) {
    short8 a[3], b[8];
#pragma unroll
    for (int t = 0; t < 3; ++t)
      a[t] = *(const short8*)(cA + lof(gi*33 + t*16 + fr, q));
#pragma unroll
    for (int nf = 0; nf < 8; ++nf)
      b[nf] = *(const short8*)(cB + lof(h*128 + nf*16 + fr, q));
#pragma unroll
    for (int t = 0; t < 3; ++t)
#pragma unroll
      for (int nf = 0; nf < 8; ++nf)
        acc[t][nf] = __builtin_amdgcn_mfma_f32_16x16x32_bf16(a[t], b[nf], acc[t][nf], 0, 0, 0);
  };

  // ---------------- K loop ----------------
  if (ACT == 0 && !isbf) {
    // fp32 fallback (cold path; runtime inputs are bf16): simple drain loop.
    for (int kc = 0; kc < 8; ++kc) {
      const int k0 = kc * 32;
      __syncthreads();
      {
        const float* ap = Af + (R0 + r0)*256 + k0 + c8;
        float4 p0 = *(const float4*)(ap);
        float4 p1 = *(const float4*)(ap + 4);
        u16 ov[8];
        ov[0]=f2bf(p0.x); ov[1]=f2bf(p0.y); ov[2]=f2bf(p0.z); ov[3]=f2bf(p0.w);
        ov[4]=f2bf(p1.x); ov[5]=f2bf(p1.y); ov[6]=f2bf(p1.z); ov[7]=f2bf(p1.w);
        *(uint4*)(sAbuf(0) + r0*32 + ((cq ^ ((r0 >> 1) & 3))*8)) = *(const uint4*)ov;
      }
      if (tid < 8) {
        const int rr = 64 + (tid >> 2);
        const float* ap = Af + (R0 + rr)*256 + k0 + c8;
        float4 p0 = *(const float4*)(ap);
        float4 p1 = *(const float4*)(ap + 4);
        u16 ov[8];
        ov[0]=f2bf(p0.x); ov[1]=f2bf(p0.y); ov[2]=f2bf(p0.z); ov[3]=f2bf(p0.w);
        ov[4]=f2bf(p1.x); ov[5]=f2bf(p1.y); ov[6]=f2bf(p1.z); ov[7]=f2bf(p1.w);
        *(uint4*)(sAbuf(0) + rr*32 + ((cq ^ ((rr >> 1) & 3))*8)) = *(const uint4*)ov;
      }
#pragma unroll
      for (int i = 0; i < 4; ++i)
        gload_lds16(Bt + (w*64 + i*16 + lr)*256 + k0 + (cq ^ swz)*8,
                    sBbuf(0) + (w*64 + i*16)*32);
      __syncthreads();            // full drain (correctness)
      computeP(sAbuf(0), sBbuf(0));
    }
  } else {
    if (ACT == 1) {
      const float f0 = fscale[tid], f1 = fshift[tid];
      WAITVM(0);
      sS[tid] = f0; sS[256 + tid] = f1;
      WAITLGKM0;
    }
    // prologue: B(0); A(0), A(1)
    issueB(0);
    VMFENCE;
    if (ACT == 0) { issueA_dma(0); issueA_dma(1); }
    else          { issueA_reg(0); issueA_reg(1); }
    if (ACT == 1) {
      __builtin_amdgcn_s_barrier();   // sS visible to all waves (raw: DMAs stay in flight)
      writeA(0);                       // compiler auto-waits regA[0]
      WAITLGKM0;
    }
    const bool sp = (ACT == 0) ? (w == 0) : (w == 3);   // special wave: 2 A ops/step
#pragma unroll
    for (int kc = 0; kc < 8; ++kc) {
      if (kc < 7) issueB(kc + 1);
      VMFENCE;
      if (kc < 6) { if (ACT == 0) issueA_dma(kc + 2); else issueA_reg(kc + 2); }
      // consume-wait for tile kc: keep [A(kc+1), B(kc+1), A(kc+2)] in flight
      if (kc < 6)       { if (sp) { WAITVM(8); } else { WAITVM(6); } }
      else if (kc == 6) { if (sp) { WAITVM(6); } else { WAITVM(5); } }
      else              { WAITVM(0); }
      __builtin_amdgcn_sched_barrier(0);
      __builtin_amdgcn_s_barrier();
      computeP(ACT == 0 ? sAbuf(kc % 3) : sAbuf(kc & 1), sBbuf(kc & 1));
      if (ACT == 1 && kc < 7) {
        writeA(kc + 1);      // auto-wait on regA slot; B/A prefetches stay in flight
        WAITLGKM0;
      }
    }
  }

  // ---- epilogue 1: T -> LDS (bf16, rows<33 only; garbage rows discarded) ----
  __syncthreads();
  u16* const Tl = smem;     // [66][264]
#pragma unroll
  for (int t = 0; t < 3; ++t)
#pragma unroll
    for (int nf = 0; nf < 8; ++nf)
#pragma unroll
      for (int r = 0; r < 4; ++r) {
        const int row = t*16 + q*4 + r;
        if (row < 33)
          Tl[(gi*33 + row)*264 + h*128 + nf*16 + fr] = f2bf(acc[t][nf][r]);
      }
  __syncthreads();

  // ---- epilogue 2: graph-local skeleton aggregation + bias + stats ----
  const int g2 = tid >> 7, cp = tid & 127;
  const size_t Gg = (size_t)blockIdx.x*2 + g2;
  float a0[33], a1[33];
#pragma unroll
  for (int d = 0; d < 33; ++d) { a0[d] = 0.f; a1[d] = 0.f; }
#pragma unroll
  for (int s = 0; s < 33; ++s) {
    const unsigned int pk = *(const unsigned int*)(Tl + (g2*33 + s)*264 + cp*2);
    const float v0 = bf2f((u16)(pk & 0xffffu)) * DINV[s];
    const float v1 = bf2f((u16)(pk >> 16)) * DINV[s];
    a0[s] += v0; a1[s] += v1;                    // self loop
#pragma unroll
    for (int i = 0; i < NBCNT[s]; ++i) { a0[NBR[s][i]] += v0; a1[NBR[s][i]] += v1; }
  }
  const float bv0 = ldin(bias, cp*2,     dtf);
  const float bv1 = ldin(bias, cp*2 + 1, dtf);
  float s10 = 0.f, s20 = 0.f, s11 = 0.f, s21 = 0.f;
  u16* hg = H + Gg * (33*256);
#pragma unroll
  for (int d = 0; d < 33; ++d) {
    const float o0 = fmaf(a0[d], DINV[d], bv0);
    const float o1 = fmaf(a1[d], DINV[d], bv1);
    const unsigned int pw = (unsigned int)f2bf(o0) | ((unsigned int)f2bf(o1) << 16);
    *(unsigned int*)(hg + d*256 + cp*2) = pw;
    s10 += o0; s20 += o0*o0; s11 += o1; s21 += o1*o1;
  }
  float* r1p = repl + (Gg & 63)*512;
  atomicAdd(r1p + cp*2,           s10);
  atomicAdd(r1p + cp*2 + 1,       s11);
  atomicAdd(r1p + 256 + cp*2,     s20);
  atomicAdd(r1p + 256 + cp*2 + 1, s21);
}

// ---- finalize BN stats -> scale/shift ----
__global__ __launch_bounds__(256) void statfin_kernel(const float* __restrict__ repl,
    const void* __restrict__ gamma, const void* __restrict__ beta, float* __restrict__ fs,
    const int* __restrict__ flag)
{
  const int c = threadIdx.x;
  const int isbf = *flag;
  float s1 = 0.f, s2 = 0.f;
  for (int r = 0; r < 64; ++r) { s1 += repl[r*512 + c]; s2 += repl[r*512 + 256 + c]; }
  const float inv = 1.f / (float)NN_TOT;
  const float mu = s1 * inv;
  const float var = s2 * inv - mu*mu;
  const float rs = rsqrtf(var + 1e-5f);
  const float sc = rs * ldin(gamma, c, isbf);
  fs[c] = sc;
  fs[256 + c] = ldin(beta, c, isbf) - mu * sc;
}

// ---- fused layer3 + mean-pool + classifier: 1 wave per graph, 4 cols/lane ----
__global__ __launch_bounds__(256) void final_kernel(const u16* __restrict__ H,
    const float* __restrict__ fs, const float* __restrict__ wq,
    const float* __restrict__ bq, void* __restrict__ outp,
    const int* __restrict__ flag)
{
  const int tid = threadIdx.x;
  const int lane = tid & 63, wv = tid >> 6;
  const size_t g = (size_t)blockIdx.x * 4 + wv;
  const int isbf = *flag;
  const int c4 = lane * 4;
  const float4 scv = *(const float4*)(fs + c4);
  const float4 shv = *(const float4*)(fs + 256 + c4);
  const u16* hg = H + g * (33*256);
  float v0 = 0.f, v1 = 0.f, v2 = 0.f, v3 = 0.f;
#pragma unroll
  for (int s = 0; s < 33; ++s) {
    float a = DINV[s];
#pragma unroll
    for (int i = 0; i < NBCNT[s]; ++i) a += DINV[NBR[s][i]];
    const float ws = DINV[s] * a * (1.f/33.f);   // column-sum of Ahat / 33 (const-folded)
    const uint2 pk = *(const uint2*)(hg + s*256 + c4);
    v0 += ws * fmaxf(0.f, fmaf(bf2f((u16)(pk.x & 0xffffu)), scv.x, shv.x));
    v1 += ws * fmaxf(0.f, fmaf(bf2f((u16)(pk.x >> 16)),     scv.y, shv.y));
    v2 += ws * fmaxf(0.f, fmaf(bf2f((u16)(pk.y & 0xffffu)), scv.z, shv.z));
    v3 += ws * fmaxf(0.f, fmaf(bf2f((u16)(pk.y >> 16)),     scv.w, shv.w));
  }
  const float4 q0 = *(const float4*)(wq + (c4+0)*4);
  const float4 q1 = *(const float4*)(wq + (c4+1)*4);
  const float4 q2 = *(const float4*)(wq + (c4+2)*4);
  const float4 q3 = *(const float4*)(wq + (c4+3)*4);
  float p0 = v0*q0.x + v1*q1.x + v2*q2.x + v3*q3.x;
  float p1 = v0*q0.y + v1*q1.y + v2*q2.y + v3*q3.y;
  float p2 = v0*q0.z + v1*q1.z + v2*q2.z + v3*q3.z;
  float p3 = v0*q0.w + v1*q1.w + v2*q2.w + v3*q3.w;
#pragma unroll
  for (int off = 32; off; off >>= 1) {
    p0 += __shfl_xor(p0, off); p1 += __shfl_xor(p1, off);
    p2 += __shfl_xor(p2, off); p3 += __shfl_xor(p3, off);
  }
  if (lane == 0) {
    if (isbf) {
      u16* o = (u16*)outp + g*4;
      o[0]=f2bf(p0+bq[0]); o[1]=f2bf(p1+bq[1]); o[2]=f2bf(p2+bq[2]); o[3]=f2bf(p3+bq[3]);
    } else {
      float* o = (float*)outp + g*4;
      o[0]=p0+bq[0]; o[1]=p1+bq[1]; o[2]=p2+bq[2]; o[3]=p3+bq[3];
    }
  }
}

extern "C" void kernel_launch(void* const* d_in, const int* in_sizes, int n_in,
                              void* d_out, int out_size, void* d_ws, size_t ws_size,
                              hipStream_t stream)
{
  const void* x   = d_in[0];
  const void* w0  = d_in[1];
  const void* b0  = d_in[2];
  const void* g0  = d_in[3];
  const void* be0 = d_in[4];
  const void* w1  = d_in[5];
  const void* b1  = d_in[6];
  const void* g1  = d_in[7];
  const void* be1 = d_in[8];
  const void* w2  = d_in[9];
  const void* b2  = d_in[10];
  const void* g2  = d_in[11];
  const void* be2 = d_in[12];
  const void* wh  = d_in[13];
  const void* bh  = d_in[14];
  const void* wc  = d_in[15];
  const void* bc  = d_in[16];

  // Workspace: 66.8 MB total.
  char* ws = (char*)d_ws;
  float* wq   = (float*)(ws + 0);          // 1024 f
  float* bq   = (float*)(ws + 4096);       // 4 f
  float* fs   = (float*)(ws + 4608);       // 3 * 512 f
  int*   flag = (int*)  (ws + 12288);      // dtype flag
  float* repl = (float*)(ws + 16384);      // 3 * 64 * 512 f
  u16*   Wt   = (u16*)  (ws + 409600);     // 3 * 65536 bf16
  u16*   A    = (u16*)  (ws + 802816);     // 135168*256 bf16 (ends at 70,008,832)
  (void)in_sizes; (void)n_in; (void)out_size; (void)ws_size;

  detect_kernel<<<1, 256, 0, stream>>>((const u16*)x, flag);
  transpose_kernel<<<48, 256, 0, stream>>>(w0, w1, w2, Wt, flag);
  init_kernel<<<65, 256, 0, stream>>>(wh, bh, wc, bc, wq, bq, repl, flag);

  // layer 0 (gemm + aggregation + stats fused)
  fused_kernel<0><<<2048, 256, 0, stream>>>(x, Wt, nullptr, nullptr, b0, A, repl, flag);
  statfin_kernel<<<1, 256, 0, stream>>>(repl, g0, be0, fs, flag);
  // layer 1 (in-place)
  fused_kernel<1><<<2048, 256, 0, stream>>>(A, Wt + 65536, fs, fs + 256, b1, A, repl + 32768, flag);
  statfin_kernel<<<1, 256, 0, stream>>>(repl + 32768, g1, be1, fs + 512, flag);
  // layer 2 (in-place)
  fused_kernel<1><<<2048, 256, 0, stream>>>(A, Wt + 131072, fs + 512, fs + 768, b2, A, repl + 65536, flag);
  statfin_kernel<<<1, 256, 0, stream>>>(repl + 65536, g2, be2, fs + 1024, flag);
  // layer 3 + pool + classifier (folded)
  final_kernel<<<1024, 256, 0, stream>>>(A, fs + 1024, wq, bq, d_out, flag);
}

// Round 8
// 395.657 us; speedup vs baseline: 1.2546x; 1.0616x over previous
//
#include <hip/hip_runtime.h>

typedef unsigned short u16;
typedef __attribute__((ext_vector_type(8))) short short8;
typedef __attribute__((ext_vector_type(4))) float floatx4;

#define NN_TOT 135168   // 4096 * 33

#define WAITVM(N) asm volatile("s_waitcnt vmcnt(" #N ")" ::: "memory")
#define WAITLGKM0 asm volatile("s_waitcnt lgkmcnt(0)" ::: "memory")
#define VMFENCE   asm volatile("" ::: "memory")   // compiler fence: pins vmem issue order

// ---- compile-time skeleton (from SKELETON_EDGES, incl. self-loops) ----
static constexpr int NBCNT[33] = {2,2,2,2,2,2,2,1,1,1,1,3,3,2,2,4,4,2,2,2,2,1,1,3,3,2,2,3,3,2,2,2,2};
static constexpr int NBR[33][4] = {
 {1,4,0,0},{0,2,0,0},{1,3,0,0},{2,7,0,0},{0,5,0,0},{4,6,0,0},{5,8,0,0},
 {3,0,0,0},{6,0,0,0},{10,0,0,0},{9,0,0,0},
 {12,13,23,0},{11,14,24,0},{11,15,0,0},{12,16,0,0},
 {13,17,19,21},{14,18,20,22},
 {15,19,0,0},{16,20,0,0},{15,17,0,0},{16,18,0,0},{15,0,0,0},{16,0,0,0},
 {11,24,25,0},{12,23,26,0},{23,27,0,0},{24,28,0,0},
 {25,29,31,0},{26,30,32,0},{27,31,0,0},{28,32,0,0},{29,27,0,0},{30,28,0,0}};
static constexpr float R2 = 0.70710678f, R3 = 0.57735027f, R4 = 0.5f, R5 = 0.44721360f;
static constexpr float DINV[33] = {R3,R3,R3,R3,R3,R3,R3, R2,R2,R2,R2, R4,R4, R3,R3, R5,R5,
                                   R3,R3,R3,R3, R2,R2, R4,R4, R3,R3, R4,R4, R3,R3,R3,R3};

__device__ __forceinline__ float bf2f(u16 u) {
  unsigned int v = ((unsigned int)u) << 16; float f; __builtin_memcpy(&f, &v, 4); return f;
}
__device__ __forceinline__ u16 f2bf(float f) {
  unsigned int u; __builtin_memcpy(&u, &f, 4);
  return (u16)((u + 0x7fffu + ((u >> 16) & 1u)) >> 16);
}
__device__ __forceinline__ float ldin(const void* p, int i, int isbf) {
  return isbf ? bf2f(((const u16*)p)[i]) : ((const float*)p)[i];
}
__device__ __forceinline__ void gload_lds16(const u16* g, u16* l) {
  __builtin_amdgcn_global_load_lds((const __attribute__((address_space(1))) unsigned int*)g,
                                   (__attribute__((address_space(3))) unsigned int*)l, 16, 0, 0);
}
// swizzled LDS offset (u16 units): row stride 32 u16; 16B chunk XOR'd by row bits
__device__ __forceinline__ int lof(int row, int qq) {
  return row*32 + ((qq ^ ((row >> 1) & 3)) * 8);
}

// ---- dtype detector (unchanged) ----
__global__ __launch_bounds__(256) void detect_kernel(const u16* __restrict__ x,
                                                     int* __restrict__ flag)
{
  __shared__ int cnt[256];
  const int t = threadIdx.x;
  int c = 0;
  for (int j = 0; j < 16; ++j) {
    u16 u = x[(t*16 + j)*2];
    int e = (u >> 7) & 0xFF;
    c += (e >= 118 && e <= 130) ? 1 : 0;
  }
  cnt[t] = c;
  __syncthreads();
  if (t == 0) {
    int s = 0;
    for (int i = 0; i < 256; ++i) s += cnt[i];
    *flag = (s > 2048) ? 1 : 0;   // 1 = bf16 inputs, 0 = fp32 inputs
  }
}

// ---- W transpose + canonicalize to bf16: Wt[n][k] = W[k][n] ----
__global__ __launch_bounds__(256) void transpose_kernel(const void* __restrict__ w0,
    const void* __restrict__ w1, const void* __restrict__ w2, u16* __restrict__ Wt,
    const int* __restrict__ flag)
{
  const int m = blockIdx.x >> 4;
  const int nb = (blockIdx.x & 15) * 16;
  const void* W = m == 0 ? w0 : (m == 1 ? w1 : w2);
  u16* O = Wt + (size_t)m * 65536;
  const int t = threadIdx.x;
  const int lane = t & 63, wv = t >> 6;
  const int isbf = *flag;
  if (isbf) {
    const u16* Wb = (const u16*)W;
#pragma unroll
    for (int nn = 0; nn < 4; ++nn) {
      const int n = nb + nn*4 + wv;
#pragma unroll
      for (int j = 0; j < 4; ++j) {
        const int k = lane + 64*j;
        O[n*256 + k] = Wb[k*256 + n];
      }
    }
  } else {
    const float* Wf = (const float*)W;
#pragma unroll
    for (int nn = 0; nn < 4; ++nn) {
      const int n = nb + nn*4 + wv;
#pragma unroll
      for (int j = 0; j < 4; ++j) {
        const int k = lane + 64*j;
        O[n*256 + k] = f2bf(Wf[k*256 + n]);
      }
    }
  }
}

// ---- init: wq = wh@wc, bq = bh@wc + bc, zero stat replicas ----
__global__ __launch_bounds__(256) void init_kernel(const void* __restrict__ wh,
    const void* __restrict__ bh, const void* __restrict__ wc, const void* __restrict__ bc,
    float* __restrict__ wq, float* __restrict__ bq, float* __restrict__ repl,
    const int* __restrict__ flag)
{
  const int idx = blockIdx.x*256 + threadIdx.x;
  for (int i = idx; i < 3*64*512; i += 65*256) repl[i] = 0.f;
  const int isbf = *flag;
  const int t = threadIdx.x;
  const int lane = t & 63;
  if (blockIdx.x < 64) {
    const int r = blockIdx.x*4 + (t >> 6);    // wq row, one per wave
    float a0=0.f, a1=0.f, a2=0.f, a3=0.f;
#pragma unroll
    for (int j = 0; j < 4; ++j) {
      const int k = lane + 64*j;
      const float w = ldin(wh, r*256 + k, isbf);
      a0 += w*ldin(wc, k*4+0, isbf); a1 += w*ldin(wc, k*4+1, isbf);
      a2 += w*ldin(wc, k*4+2, isbf); a3 += w*ldin(wc, k*4+3, isbf);
    }
#pragma unroll
    for (int off = 32; off; off >>= 1) {
      a0 += __shfl_xor(a0, off); a1 += __shfl_xor(a1, off);
      a2 += __shfl_xor(a2, off); a3 += __shfl_xor(a3, off);
    }
    if (lane == 0) { wq[r*4+0]=a0; wq[r*4+1]=a1; wq[r*4+2]=a2; wq[r*4+3]=a3; }
  } else if (t < 64) {
    float s0=0.f, s1=0.f, s2=0.f, s3=0.f;
#pragma unroll
    for (int j = 0; j < 4; ++j) {
      const int k = lane + 64*j;
      const float b = ldin(bh, k, isbf);
      s0 += b*ldin(wc, k*4+0, isbf); s1 += b*ldin(wc, k*4+1, isbf);
      s2 += b*ldin(wc, k*4+2, isbf); s3 += b*ldin(wc, k*4+3, isbf);
    }
#pragma unroll
    for (int off = 32; off; off >>= 1) {
      s0 += __shfl_xor(s0, off); s1 += __shfl_xor(s1, off);
      s2 += __shfl_xor(s2, off); s3 += __shfl_xor(s3, off);
    }
    if (lane == 0) {
      bq[0] = s0 + ldin(bc, 0, isbf); bq[1] = s1 + ldin(bc, 1, isbf);
      bq[2] = s2 + ldin(bc, 2, isbf); bq[3] = s3 + ldin(bc, 3, isbf);
    }
  }
}

// ---- FUSED layer: H = Ahat @ (act(Ag) @ W) + b, plus BN stats ----
// OCCUPANCY RESTRUCTURE: 512 threads / 8 waves per block, 2 graphs (66 rows).
// Wave w: graph gi = w>>2, col-quarter h = w&3 (64 cols) -> acc[3][4] = 48
// accum regs/wave (was 96). Target <=128 total regs -> 4 waves/SIMD (16/CU).
// Pipeline: 1-step prefetch, counted vmcnt (A+B of next tile stay in flight
// across the raw barrier), TRIPLE-buffered A and B (mod-3 rotation makes the
// prefetch DMA target provably disjoint from any buffer still being read).
template<int ACT>
__global__ __launch_bounds__(512, 4) void fused_kernel(
    const void* __restrict__ Ag, const u16* __restrict__ Bt,
    const float* __restrict__ fscale, const float* __restrict__ fshift,
    const void* __restrict__ bias, u16* __restrict__ H,
    float* __restrict__ repl, const int* __restrict__ flag)
{
  // u16 units: sA[3] @ i*2592 (81 rows x 32), sB[3] @ 7776 + i*8192,
  // sS f32[512] @ 32352. Total 33376 u16 = 66752 B -> 2 blocks/CU by LDS.
  // Epilogue overlays Tl = u16[66][264] @ 0 (17424 u16).
  __shared__ __align__(16) u16 smem[33376];
  const int tid = threadIdx.x;
  const int lane = tid & 63, w = tid >> 6;       // 8 waves
  const int gi = w >> 2, h = w & 3;              // graph, 64-col quarter
  const int fr = lane & 15, q = lane >> 4;
  const int lr = lane >> 2, cq = lane & 3;
  const int swz = (lr >> 1) & 3;
  const size_t R0 = (size_t)blockIdx.x * 66;
  const int dtf = *flag;
  const int isbf = (ACT == 0) ? dtf : 1;
  const u16* Ab = (const u16*)Ag;
  const float* Af = (const float*)Ag;
  float* const sS = (float*)(smem + 32352);

  floatx4 acc[3][4];
#pragma unroll
  for (int t = 0; t < 3; ++t)
#pragma unroll
    for (int j = 0; j < 4; ++j) acc[t][j] = (floatx4){0.f, 0.f, 0.f, 0.f};

  auto sAbuf = [&](int i) -> u16* { return smem + i*2592; };
  auto sBbuf = [&](int i) -> u16* { return smem + 7776 + i*8192; };

  // ---- staging: A first, then B (so ACT1's regA dep-wait leaves B in flight)
  auto issueA_dma = [&](int t) {           // ACT0 bf16: waves 0..4, 1 DMA each
    if (w < 5) {
      u16* dst = sAbuf(t % 3);
      size_t rowg = R0 + w*16 + lr;
      const size_t rmax = R0 + 65;
      if (rowg > rmax) rowg = rmax;        // rows 66..79: clamp (garbage, masked)
      gload_lds16(Ab + rowg*256 + t*32 + (cq ^ swz)*8, dst + (w*16)*32);
    }
  };
  uint4 regA;
  auto issueA_reg = [&](int t) {           // ACT1: threads 0..263, 1 load each
    if (tid < 264)
      regA = *(const uint4*)(Ab + (R0 + (tid >> 2))*256 + t*32 + (tid & 3)*8);
  };
  auto issueB = [&](int t) {               // all waves: 2 DMA each (256 rows)
    u16* dst = sBbuf(t % 3);
#pragma unroll
    for (int i = 0; i < 2; ++i)
      gload_lds16(Bt + (w*32 + i*16 + lr)*256 + t*32 + (cq ^ swz)*8,
                  dst + (w*32 + i*16)*32);
  };
  auto writeA = [&](int t) {               // ACT1: BN-ReLU from sS, swizzled ds_write
    if (tid < 264) {
      const int row = tid >> 2, cc = tid & 3;
      const float4 s0 = *(const float4*)(sS + t*32 + cc*8);
      const float4 s1 = *(const float4*)(sS + t*32 + cc*8 + 4);
      const float4 t0 = *(const float4*)(sS + 256 + t*32 + cc*8);
      const float4 t1 = *(const float4*)(sS + 256 + t*32 + cc*8 + 4);
      const float sc[8] = {s0.x,s0.y,s0.z,s0.w, s1.x,s1.y,s1.z,s1.w};
      const float sh[8] = {t0.x,t0.y,t0.z,t0.w, t1.x,t1.y,t1.z,t1.w};
      const u16* us = (const u16*)&regA;
      u16 ov[8];
#pragma unroll
      for (int j = 0; j < 8; ++j)
        ov[j] = f2bf(fmaxf(0.f, fmaf(bf2f(us[j]), sc[j], sh[j])));
      *(uint4*)(sAbuf(t % 3) + row*32 + ((cc ^ ((row >> 1) & 3))*8)) = *(const uint4*)ov;
    }
  };

  auto computeP = [&](const u16* cA, const u16* cB) {
    short8 a[3], b[4];
#pragma unroll
    for (int t = 0; t < 3; ++t)
      a[t] = *(const short8*)(cA + lof(gi*33 + t*16 + fr, q));   // rows<=80 in 81-row buf
#pragma unroll
    for (int nf = 0; nf < 4; ++nf)
      b[nf] = *(const short8*)(cB + lof(h*64 + nf*16 + fr, q));
#pragma unroll
    for (int t = 0; t < 3; ++t)
#pragma unroll
      for (int nf = 0; nf < 4; ++nf)
        acc[t][nf] = __builtin_amdgcn_mfma_f32_16x16x32_bf16(a[t], b[nf], acc[t][nf], 0, 0, 0);
  };

  // ---------------- K loop ----------------
  if (ACT == 0 && !isbf) {
    // fp32 fallback (cold path; runtime inputs are bf16): single-buf drain loop.
    for (int kc = 0; kc < 8; ++kc) {
      const int k0 = kc * 32;
      __syncthreads();
      if (tid < 264) {
        const int row = tid >> 2, cc = tid & 3;
        const float* ap = Af + (R0 + row)*256 + k0 + cc*8;
        float4 p0 = *(const float4*)(ap);
        float4 p1 = *(const float4*)(ap + 4);
        u16 ov[8];
        ov[0]=f2bf(p0.x); ov[1]=f2bf(p0.y); ov[2]=f2bf(p0.z); ov[3]=f2bf(p0.w);
        ov[4]=f2bf(p1.x); ov[5]=f2bf(p1.y); ov[6]=f2bf(p1.z); ov[7]=f2bf(p1.w);
        *(uint4*)(sAbuf(0) + row*32 + ((cc ^ ((row >> 1) & 3))*8)) = *(const uint4*)ov;
      }
#pragma unroll
      for (int i = 0; i < 2; ++i)
        gload_lds16(Bt + (w*32 + i*16 + lr)*256 + k0 + (cq ^ swz)*8,
                    sBbuf(0) + (w*32 + i*16)*32);
      __syncthreads();            // full drain (correctness)
      computeP(sAbuf(0), sBbuf(0));
    }
  } else {
    if (ACT == 1) {
      if (tid < 256) { const float f0 = fscale[tid], f1 = fshift[tid];
                       sS[tid] = f0; sS[256 + tid] = f1; }
    }
    // prologue: batch(0)
    if (ACT == 0) issueA_dma(0); else issueA_reg(0);
    VMFENCE;
    issueB(0);
    if (ACT == 1) {
      WAITLGKM0;                       // own sS ds_writes drained
      __builtin_amdgcn_s_barrier();    // sS visible to all waves
      writeA(0);                       // dep-waits regA (vmcnt(2): B(0) stays in flight)
      WAITLGKM0;
    }
#pragma unroll
    for (int kc = 0; kc < 8; ++kc) {
      if (kc < 7) {
        if (ACT == 0) issueA_dma(kc + 1); else issueA_reg(kc + 1);
        VMFENCE;
        issueB(kc + 1);
      }
      // consume-wait for tile kc: leave exactly batch(kc+1) in flight
      if (kc < 7) { if (w < 5) { WAITVM(3); } else { WAITVM(2); } }
      else        { WAITVM(0); }
      __builtin_amdgcn_sched_barrier(0);
      __builtin_amdgcn_s_barrier();
      computeP(sAbuf(kc % 3), sBbuf(kc % 3));
      if (ACT == 1 && kc < 7) {
        writeA(kc + 1);                // after this step's barrier: target buf is idle
        WAITLGKM0;
      }
    }
  }

  // ---- epilogue 1: T -> LDS (bf16, rows<33 only; garbage rows discarded) ----
  __syncthreads();
  u16* const Tl = smem;     // [66][264]
#pragma unroll
  for (int t = 0; t < 3; ++t)
#pragma unroll
    for (int nf = 0; nf < 4; ++nf)
#pragma unroll
      for (int r = 0; r < 4; ++r) {
        const int row = t*16 + q*4 + r;
        if (row < 33)
          Tl[(gi*33 + row)*264 + h*64 + nf*16 + fr] = f2bf(acc[t][nf][r]);
      }
  __syncthreads();

  // ---- epilogue 2: graph-local skeleton aggregation + bias + stats ----
  // 512 threads: (graph g2 = tid>>8, single column c = tid&255)
  const int g2 = tid >> 8, c = tid & 255;
  const size_t Gg = (size_t)blockIdx.x*2 + g2;
  float a0[33];
#pragma unroll
  for (int d = 0; d < 33; ++d) a0[d] = 0.f;
#pragma unroll
  for (int s = 0; s < 33; ++s) {
    const float v = bf2f(Tl[(g2*33 + s)*264 + c]) * DINV[s];
    a0[s] += v;                                  // self loop
#pragma unroll
    for (int i = 0; i < NBCNT[s]; ++i) a0[NBR[s][i]] += v;
  }
  const float bv = ldin(bias, c, dtf);
  float s1 = 0.f, s2 = 0.f;
  u16* hg = H + Gg * (33*256);
#pragma unroll
  for (int d = 0; d < 33; ++d) {
    const float o = fmaf(a0[d], DINV[d], bv);
    hg[d*256 + c] = f2bf(o);
    s1 += o; s2 += o*o;
  }
  float* r1p = repl + (Gg & 63)*512;
  atomicAdd(r1p + c,       s1);
  atomicAdd(r1p + 256 + c, s2);
}

// ---- finalize BN stats -> scale/shift ----
__global__ __launch_bounds__(256) void statfin_kernel(const float* __restrict__ repl,
    const void* __restrict__ gamma, const void* __restrict__ beta, float* __restrict__ fs,
    const int* __restrict__ flag)
{
  const int c = threadIdx.x;
  const int isbf = *flag;
  float s1 = 0.f, s2 = 0.f;
  for (int r = 0; r < 64; ++r) { s1 += repl[r*512 + c]; s2 += repl[r*512 + 256 + c]; }
  const float inv = 1.f / (float)NN_TOT;
  const float mu = s1 * inv;
  const float var = s2 * inv - mu*mu;
  const float rs = rsqrtf(var + 1e-5f);
  const float sc = rs * ldin(gamma, c, isbf);
  fs[c] = sc;
  fs[256 + c] = ldin(beta, c, isbf) - mu * sc;
}

// ---- fused layer3 + mean-pool + classifier: 1 wave per graph, 4 cols/lane ----
__global__ __launch_bounds__(256) void final_kernel(const u16* __restrict__ H,
    const float* __restrict__ fs, const float* __restrict__ wq,
    const float* __restrict__ bq, void* __restrict__ outp,
    const int* __restrict__ flag)
{
  const int tid = threadIdx.x;
  const int lane = tid & 63, wv = tid >> 6;
  const size_t g = (size_t)blockIdx.x * 4 + wv;
  const int isbf = *flag;
  const int c4 = lane * 4;
  const float4 scv = *(const float4*)(fs + c4);
  const float4 shv = *(const float4*)(fs + 256 + c4);
  const u16* hg = H + g * (33*256);
  float v0 = 0.f, v1 = 0.f, v2 = 0.f, v3 = 0.f;
#pragma unroll
  for (int s = 0; s < 33; ++s) {
    float a = DINV[s];
#pragma unroll
    for (int i = 0; i < NBCNT[s]; ++i) a += DINV[NBR[s][i]];
    const float ws = DINV[s] * a * (1.f/33.f);   // column-sum of Ahat / 33 (const-folded)
    const uint2 pk = *(const uint2*)(hg + s*256 + c4);
    v0 += ws * fmaxf(0.f, fmaf(bf2f((u16)(pk.x & 0xffffu)), scv.x, shv.x));
    v1 += ws * fmaxf(0.f, fmaf(bf2f((u16)(pk.x >> 16)),     scv.y, shv.y));
    v2 += ws * fmaxf(0.f, fmaf(bf2f((u16)(pk.y & 0xffffu)), scv.z, shv.z));
    v3 += ws * fmaxf(0.f, fmaf(bf2f((u16)(pk.y >> 16)),     scv.w, shv.w));
  }
  const float4 q0 = *(const float4*)(wq + (c4+0)*4);
  const float4 q1 = *(const float4*)(wq + (c4+1)*4);
  const float4 q2 = *(const float4*)(wq + (c4+2)*4);
  const float4 q3 = *(const float4*)(wq + (c4+3)*4);
  float p0 = v0*q0.x + v1*q1.x + v2*q2.x + v3*q3.x;
  float p1 = v0*q0.y + v1*q1.y + v2*q2.y + v3*q3.y;
  float p2 = v0*q0.z + v1*q1.z + v2*q2.z + v3*q3.z;
  float p3 = v0*q0.w + v1*q1.w + v2*q2.w + v3*q3.w;
#pragma unroll
  for (int off = 32; off; off >>= 1) {
    p0 += __shfl_xor(p0, off); p1 += __shfl_xor(p1, off);
    p2 += __shfl_xor(p2, off); p3 += __shfl_xor(p3, off);
  }
  if (lane == 0) {
    if (isbf) {
      u16* o = (u16*)outp + g*4;
      o[0]=f2bf(p0+bq[0]); o[1]=f2bf(p1+bq[1]); o[2]=f2bf(p2+bq[2]); o[3]=f2bf(p3+bq[3]);
    } else {
      float* o = (float*)outp + g*4;
      o[0]=p0+bq[0]; o[1]=p1+bq[1]; o[2]=p2+bq[2]; o[3]=p3+bq[3];
    }
  }
}

extern "C" void kernel_launch(void* const* d_in, const int* in_sizes, int n_in,
                              void* d_out, int out_size, void* d_ws, size_t ws_size,
                              hipStream_t stream)
{
  const void* x   = d_in[0];
  const void* w0  = d_in[1];
  const void* b0  = d_in[2];
  const void* g0  = d_in[3];
  const void* be0 = d_in[4];
  const void* w1  = d_in[5];
  const void* b1  = d_in[6];
  const void* g1  = d_in[7];
  const void* be1 = d_in[8];
  const void* w2  = d_in[9];
  const void* b2  = d_in[10];
  const void* g2  = d_in[11];
  const void* be2 = d_in[12];
  const void* wh  = d_in[13];
  const void* bh  = d_in[14];
  const void* wc  = d_in[15];
  const void* bc  = d_in[16];

  // Workspace: 66.8 MB total.
  char* ws = (char*)d_ws;
  float* wq   = (float*)(ws + 0);          // 1024 f
  float* bq   = (float*)(ws + 4096);       // 4 f
  float* fs   = (float*)(ws + 4608);       // 3 * 512 f
  int*   flag = (int*)  (ws + 12288);      // dtype flag
  float* repl = (float*)(ws + 16384);      // 3 * 64 * 512 f
  u16*   Wt   = (u16*)  (ws + 409600);     // 3 * 65536 bf16
  u16*   A    = (u16*)  (ws + 802816);     // 135168*256 bf16 (ends at 70,008,832)
  (void)in_sizes; (void)n_in; (void)out_size; (void)ws_size;

  detect_kernel<<<1, 256, 0, stream>>>((const u16*)x, flag);
  transpose_kernel<<<48, 256, 0, stream>>>(w0, w1, w2, Wt, flag);
  init_kernel<<<65, 256, 0, stream>>>(wh, bh, wc, bc, wq, bq, repl, flag);

  // layer 0 (gemm + aggregation + stats fused)
  fused_kernel<0><<<2048, 512, 0, stream>>>(x, Wt, nullptr, nullptr, b0, A, repl, flag);
  statfin_kernel<<<1, 256, 0, stream>>>(repl, g0, be0, fs, flag);
  // layer 1 (in-place)
  fused_kernel<1><<<2048, 512, 0, stream>>>(A, Wt + 65536, fs, fs + 256, b1, A, repl + 32768, flag);
  statfin_kernel<<<1, 256, 0, stream>>>(repl + 32768, g1, be1, fs + 512, flag);
  // layer 2 (in-place)
  fused_kernel<1><<<2048, 512, 0, stream>>>(A, Wt + 131072, fs + 512, fs + 768, b2, A, repl + 65536, flag);
  statfin_kernel<<<1, 256, 0, stream>>>(repl + 65536, g2, be2, fs + 1024, flag);
  // layer 3 + pool + classifier (folded)
  final_kernel<<<1024, 256, 0, stream>>>(A, fs + 1024, wq, bq, d_out, flag);
}